// Round 7
// baseline (547.662 us; speedup 1.0000x reference)
//
#include <hip/hip_runtime.h>

typedef _Float16 half8 __attribute__((ext_vector_type(8)));
typedef __fp16 fp16x2 __attribute__((ext_vector_type(2)));
typedef short short8 __attribute__((ext_vector_type(8)));
typedef short short4v __attribute__((ext_vector_type(4)));
typedef float floatx4 __attribute__((ext_vector_type(4)));

#define LOG2E 1.4426950408889634f

#define GLDS16(g, l) __builtin_amdgcn_global_load_lds( \
    (const __attribute__((address_space(1))) unsigned int*)(g), \
    (__attribute__((address_space(3))) unsigned int*)(l), 16, 0, 0)

static __device__ __forceinline__ short f2bf(float f){
  union { float f; unsigned u; } v; v.f = f;
  unsigned r = v.u + 0x7fffu + ((v.u >> 16) & 1u);
  return (short)(r >> 16);
}
static __device__ __forceinline__ float bf2f(short s){
  union { unsigned u; float f; } v; v.u = ((unsigned)(unsigned short)s) << 16;
  return v.f;
}

// ---- X/M fp32 -> fragment-major bf16 hi/lo.  Frag layout: [kt(32)][ntile(256)][64][8]
__global__ __launch_bounds__(256) void kconvA(const float* __restrict__ X,
                                              const float* __restrict__ Mm,
                                              short* __restrict__ XFh, short* __restrict__ XFl,
                                              short* __restrict__ MFh, short* __restrict__ MFl){
  int b = blockIdx.x;                       // 512: src=b>>8, ntile=b&255
  int t = threadIdx.x, w = t >> 6, l = t & 63, quad = l >> 4;
  int srcsel = b >> 8, ntile = b & 255;
  const float* A = srcsel ? Mm : X;
  short* oh = srcsel ? MFh : XFh;
  short* ol = srcsel ? MFl : XFl;
  int row = ntile*16 + (l & 15);
  #pragma unroll
  for (int i = 0; i < 8; i++){
    int kt = w*8 + i;
    const float* p = A + (size_t)row*1024 + kt*32 + quad*8;
    float4 v0 = *(const float4*)p, v1 = *(const float4*)(p + 4);
    float vv[8] = {v0.x,v0.y,v0.z,v0.w,v1.x,v1.y,v1.z,v1.w};
    short8 hh, ll;
    #pragma unroll
    for (int j = 0; j < 8; j++){
      short hb = f2bf(vv[j]); hh[j] = hb; ll[j] = f2bf(vv[j] - bf2f(hb));
    }
    size_t off = ((size_t)kt*256 + ntile)*512 + l*8;
    *(short8*)&oh[off] = hh;
    *(short8*)&ol[off] = ll;
  }
}

// ---- Wq/Wk/Wv fp32 [h][1024][64] -> fragment-major bf16 hi/lo, LDS-staged coalesced
__global__ __launch_bounds__(256) void kconvW2(const float* __restrict__ Wq,
                                               const float* __restrict__ Wk,
                                               const float* __restrict__ Wv,
                                               short* __restrict__ WFh, short* __restrict__ WFl){
  __shared__ float T[128][68];
  int bidx = blockIdx.x, g = blockIdx.y;    // bidx 0..47, g 0..7 (4 kt each)
  int mat = bidx >> 4, h = bidx & 15;
  const float* W = (mat == 0 ? Wq : (mat == 1 ? Wk : Wv)) + (size_t)h*65536;
  int t = threadIdx.x, w = t >> 6, l = t & 63, quad = (l >> 4) & 3, fl = l & 15;
  #pragma unroll
  for (int p = 0; p < 32; p++){
    int idx = p*256 + t, row = idx >> 6, col = idx & 63;
    T[row][col] = W[(size_t)(g*128 + row)*64 + col];
  }
  __syncthreads();
  for (int ktl = 0; ktl < 4; ktl++){
    short8 hh, ll;
    #pragma unroll
    for (int j = 0; j < 8; j++){
      float v = T[ktl*32 + quad*8 + j][w*16 + fl];
      short hb = f2bf(v); hh[j] = hb; ll[j] = f2bf(v - bf2f(hb));
    }
    size_t frag = ((size_t)bidx*32 + g*4 + ktl)*4 + w;
    *(short8*)&WFh[frag*512 + l*8] = hh;
    *(short8*)&WFl[frag*512 + l*8] = ll;
  }
}

// ---- mask -> bitmask (row orientation): bits[n*128 + kw] bit i = mask[n][kw*32+i]
__global__ __launch_bounds__(256) void kmaskpack(const int* __restrict__ mask,
                                                 unsigned* __restrict__ bits){
  int w = blockIdx.x * 256 + threadIdx.x;          // 4096*128 words
  const int* p = mask + (size_t)w * 32;
  unsigned b = 0;
  #pragma unroll
  for (int i = 0; i < 32; i++) b |= (p[i] != 0) ? (1u << i) : 0u;
  bits[w] = b;
}

// ---- fp32 [R][C] (z-batch) -> transposed bf16 hi/lo [C][R]  (for Wo)
__global__ __launch_bounds__(256) void ktransw(const float* __restrict__ src,
                                               short* __restrict__ dsth,
                                               short* __restrict__ dstl,
                                               int R, int C){
  __shared__ float tile[32][33];
  size_t boff = (size_t)blockIdx.z * R * C;
  src += boff; dsth += boff; dstl += boff;
  int r0 = blockIdx.y*32, c0 = blockIdx.x*32;
  int t = threadIdx.x, tr = t >> 3, tc = (t & 7)*4;
  const float* s = src + (size_t)(r0 + tr)*C + c0 + tc;
  #pragma unroll
  for (int i = 0; i < 4; i++) tile[tr][tc + i] = s[i];
  __syncthreads();
  short* dh = dsth + (size_t)(c0 + tr)*R + r0 + tc;
  short* dl = dstl + (size_t)(c0 + tr)*R + r0 + tc;
  #pragma unroll
  for (int i = 0; i < 4; i++){
    float v = tile[tc + i][tr];
    short hb = f2bf(v);
    dh[i] = hb; dl[i] = f2bf(v - bf2f(hb));
  }
}

// ---- QKV projection: fragment-major in/out (Q/K f16 hi/lo, V f16). Q pre-scaled by log2(e).
__global__ __launch_bounds__(256,2) void kproj2(
    const short* __restrict__ XFh, const short* __restrict__ XFl,
    const short* __restrict__ MFh, const short* __restrict__ MFl,
    const short* __restrict__ WFh, const short* __restrict__ WFl,
    _Float16* __restrict__ QFh, _Float16* __restrict__ QFl,
    _Float16* __restrict__ KFh, _Float16* __restrict__ KFl,
    _Float16* __restrict__ VF)
{
  __shared__ short AhL[4096], AlL[4096], BhL[2048], BlL[2048];
  int cb = blockIdx.x, rb = blockIdx.y;
  int mat = cb >> 4, h = cb & 15;
  const short* Ah = (mat == 0) ? XFh : MFh;
  const short* Al = (mat == 0) ? XFl : MFl;
  int t = threadIdx.x, w = t >> 6, l = t & 63, quad = l >> 4, ln = l & 15;
  floatx4 acc[2][4] = {};
  for (int kt = 0; kt < 32; kt++){
    __syncthreads();
    size_t abase = ((size_t)kt*256 + rb*8)*512;
    #pragma unroll
    for (int i = 0; i < 2; i++){
      int cidx = i*256 + t;
      GLDS16(Ah + abase + cidx*8, &AhL[(i*256 + w*64)*8]);
      GLDS16(Al + abase + cidx*8, &AlL[(i*256 + w*64)*8]);
    }
    size_t bbase = (((size_t)cb*32 + kt)*4)*512;
    GLDS16(WFh + bbase + t*8, &BhL[(w*64)*8]);
    GLDS16(WFl + bbase + t*8, &BlL[(w*64)*8]);
    __syncthreads();
    short8 bh[4], bl[4];
    #pragma unroll
    for (int nt = 0; nt < 4; nt++){
      bh[nt] = *(short8*)&BhL[nt*512 + l*8];
      bl[nt] = *(short8*)&BlL[nt*512 + l*8];
    }
    #pragma unroll
    for (int mt = 0; mt < 2; mt++){
      short8 ah = *(short8*)&AhL[(w*2 + mt)*512 + l*8];
      short8 al = *(short8*)&AlL[(w*2 + mt)*512 + l*8];
      #pragma unroll
      for (int nt = 0; nt < 4; nt++){
        acc[mt][nt] = __builtin_amdgcn_mfma_f32_16x16x32_bf16(ah, bh[nt], acc[mt][nt], 0, 0, 0);
        acc[mt][nt] = __builtin_amdgcn_mfma_f32_16x16x32_bf16(ah, bl[nt], acc[mt][nt], 0, 0, 0);
        acc[mt][nt] = __builtin_amdgcn_mfma_f32_16x16x32_bf16(al, bh[nt], acc[mt][nt], 0, 0, 0);
      }
    }
  }
  int row0 = rb*128;
  #pragma unroll
  for (int mt = 0; mt < 2; mt++)
    #pragma unroll
    for (int nt = 0; nt < 4; nt++)
      #pragma unroll
      for (int rg = 0; rg < 4; rg++){
        int n = row0 + w*32 + mt*16 + quad*4 + rg;
        int c = nt*16 + ln;
        float v = acc[mt][nt][rg];
        if (mat == 2){
          int lane2 = ln + (((n >> 3) & 3) << 4);
          VF[(((size_t)h*128 + (n >> 5))*4 + nt)*512 + lane2*8 + (n & 7)] = (_Float16)v;
        } else {
          if (mat == 0) v *= LOG2E;             // log2-domain logits
          _Float16 hi = (_Float16)v;
          _Float16 lo = (_Float16)(v - (float)hi);
          int lane2 = (n & 15) + (((c >> 3) & 3) << 4);
          size_t off = (((size_t)h*256 + (n >> 4))*2 + (c >> 5))*512 + lane2*8 + (c & 7);
          if (mat == 0){ QFh[off] = hi; QFl[off] = lo; }
          else         { KFh[off] = hi; KFl[off] = lo; }
        }
      }
}

// ---- flash attention v4: K-split 2 (1024 blocks), log2 softmax, LUT-min masking,
//      packed cvt; partials (O,m,l) fp32 -> kcomb
__global__ __launch_bounds__(256,3) void kattn4(
    const _Float16* __restrict__ QFh, const _Float16* __restrict__ QFl,
    const _Float16* __restrict__ KFh, const _Float16* __restrict__ KFl,
    const _Float16* __restrict__ VF, const unsigned* __restrict__ bits,
    float* __restrict__ OP, float2* __restrict__ ML)
{
  __shared__ _Float16 KBh[8192], KBl[8192], VB[8192];
  __shared__ _Float16 Pscr[4][16][36];
  __shared__ float MLUT[16][4];
  int bx = blockIdx.x, h = bx & 15, qb = (bx >> 4) & 31, s = bx >> 9;
  int hq = bx & 511, q0 = qb*128;
  int t = threadIdx.x, w = t >> 6, l = t & 63, quad = l >> 4, ln = l & 15;

  if (t < 16){
    #pragma unroll
    for (int rg = 0; rg < 4; rg++)
      MLUT[t][rg] = ((t >> rg) & 1) ? 1e30f : -1e30f;
  }

  half8 qh[2][2], ql[2][2];
  #pragma unroll
  for (int nt2 = 0; nt2 < 2; nt2++)
    #pragma unroll
    for (int kc = 0; kc < 2; kc++){
      size_t off = (((size_t)h*256 + qb*8 + w*2 + nt2)*2 + kc)*512 + l*8;
      qh[nt2][kc] = *(const half8*)&QFh[off];
      ql[nt2][kc] = *(const half8*)&QFl[off];
    }

  floatx4 o[2][4] = {};
  float mst[2] = {-1e30f, -1e30f}, lst[2] = {0.f, 0.f};

  for (int kt = s*16; kt < s*16 + 16; kt++){
    __syncthreads();
    size_t kb = (size_t)h*262144 + (size_t)kt*8192;
    #pragma unroll
    for (int i = 0; i < 4; i++){
      int cidx = i*256 + t;
      GLDS16(KFh + kb + cidx*8, &KBh[(i*256 + w*64)*8]);
      GLDS16(KFl + kb + cidx*8, &KBl[(i*256 + w*64)*8]);
      GLDS16(VF  + kb + cidx*8, &VB [(i*256 + w*64)*8]);
    }
    uint4 mw[2];
    mw[0] = *(const uint4*)&bits[(size_t)(q0 + w*32 + ln)*128 + kt*4];
    mw[1] = *(const uint4*)&bits[(size_t)(q0 + w*32 + 16 + ln)*128 + kt*4];
    __syncthreads();

    // S^T = Khi*Qhi + Klo*Qhi + Khi*Qlo  (log2-domain, K-frags read once)
    floatx4 st[2][8] = {};
    #pragma unroll
    for (int kc = 0; kc < 2; kc++)
      #pragma unroll
      for (int m8 = 0; m8 < 8; m8++){
        half8 kh = *(half8*)&KBh[(m8*2 + kc)*512 + l*8];
        half8 kl = *(half8*)&KBl[(m8*2 + kc)*512 + l*8];
        #pragma unroll
        for (int nt2 = 0; nt2 < 2; nt2++){
          st[nt2][m8] = __builtin_amdgcn_mfma_f32_16x16x32_f16(kh, qh[nt2][kc], st[nt2][m8], 0, 0, 0);
          st[nt2][m8] = __builtin_amdgcn_mfma_f32_16x16x32_f16(kl, qh[nt2][kc], st[nt2][m8], 0, 0, 0);
          st[nt2][m8] = __builtin_amdgcn_mfma_f32_16x16x32_f16(kh, ql[nt2][kc], st[nt2][m8], 0, 0, 0);
        }
      }

    #pragma unroll
    for (int nt2 = 0; nt2 < 2; nt2++){
      const unsigned* mwp = (const unsigned*)&mw[nt2];
      // masking via LUT-min: 1 ds_read_b128 + 4 v_min per m8
      #pragma unroll
      for (int m8 = 0; m8 < 8; m8++){
        unsigned nib = (mwp[m8 >> 1] >> ((m8 & 1)*16 + quad*4)) & 15u;
        floatx4 lv = *(floatx4*)&MLUT[nib][0];
        #pragma unroll
        for (int rg = 0; rg < 4; rg++)
          st[nt2][m8][rg] = fminf(st[nt2][m8][rg], lv[rg]);
      }
      float mx = st[nt2][0][0];
      #pragma unroll
      for (int m8 = 0; m8 < 8; m8++)
        #pragma unroll
        for (int rg = 0; rg < 4; rg++) mx = fmaxf(mx, st[nt2][m8][rg]);
      mx = fmaxf(mx, __shfl_xor(mx, 16));
      mx = fmaxf(mx, __shfl_xor(mx, 32));
      float mnew = fmaxf(mst[nt2], mx);
      float alpha = exp2f(mst[nt2] - mnew);
      mst[nt2] = mnew;
      lst[nt2] *= alpha;
      #pragma unroll
      for (int vt = 0; vt < 4; vt++) o[nt2][vt] *= alpha;
      float ssum = 0.f;
      #pragma unroll
      for (int m8 = 0; m8 < 8; m8++)
        #pragma unroll
        for (int rg = 0; rg < 4; rg++){
          float p = exp2f(st[nt2][m8][rg] - mnew);
          st[nt2][m8][rg] = p; ssum += p;
        }
      ssum += __shfl_xor(ssum, 16);
      ssum += __shfl_xor(ssum, 32);
      lst[nt2] += ssum;

      // PV per 32-k chunk: packed cvt + b32 P writes (same-wave scratch)
      #pragma unroll
      for (int c = 0; c < 4; c++){
        #pragma unroll
        for (int tt = 0; tt < 2; tt++){
          int m8 = c*2 + tt;
          fp16x2 p01 = __builtin_amdgcn_cvt_pkrtz(st[nt2][m8][0], st[nt2][m8][1]);
          fp16x2 p23 = __builtin_amdgcn_cvt_pkrtz(st[nt2][m8][2], st[nt2][m8][3]);
          *(fp16x2*)&Pscr[w][ln][tt*16 + quad*4]     = p01;
          *(fp16x2*)&Pscr[w][ln][tt*16 + quad*4 + 2] = p23;
        }
        half8 pf = *(half8*)&Pscr[w][ln][quad*8];
        #pragma unroll
        for (int vt = 0; vt < 4; vt++){
          half8 vf = *(half8*)&VB[(c*4 + vt)*512 + l*8];
          o[nt2][vt] = __builtin_amdgcn_mfma_f32_16x16x32_f16(vf, pf, o[nt2][vt], 0, 0, 0);
        }
      }
    }
  }

  // epilogue: unnormalized partials + (m,l)
  #pragma unroll
  for (int nt2 = 0; nt2 < 2; nt2++){
    int ql2 = w*32 + nt2*16 + ln;
    size_t pb = (((size_t)hq*2 + s)*128 + ql2)*64;
    #pragma unroll
    for (int vt = 0; vt < 4; vt++)
      *(floatx4*)&OP[pb + vt*16 + quad*4] = o[nt2][vt];
    if (quad == 0){
      float2 m2; m2.x = mst[nt2]; m2.y = lst[nt2];
      ML[((size_t)hq*2 + s)*128 + ql2] = m2;
    }
  }
}

// ---- combine two K-halves: O = (w0*O0 + w1*O1) / (w0*l0 + w1*l1)
__global__ __launch_bounds__(256) void kcomb(const float* __restrict__ OP,
                                             const float2* __restrict__ ML,
                                             short* __restrict__ Ows){
  int hq = blockIdx.x, h = hq & 15, qb = hq >> 4;
  int t = threadIdx.x;
  #pragma unroll
  for (int i = 0; i < 8; i++){
    int idx = i*256 + t;                 // 2048 = 128 q x 16 vgroups
    int q = idx >> 4, vg = idx & 15;
    float2 a = ML[((size_t)hq*2 + 0)*128 + q];
    float2 b = ML[((size_t)hq*2 + 1)*128 + q];
    float m = fmaxf(a.x, b.x);
    float w0 = exp2f(a.x - m), w1 = exp2f(b.x - m);
    float lsum = w0*a.y + w1*b.y;
    float inv = (lsum > 0.f) ? (1.f / lsum) : 0.f;
    const float* p0 = &OP[(((size_t)hq*2 + 0)*128 + q)*64 + vg*4];
    const float* p1 = &OP[(((size_t)hq*2 + 1)*128 + q)*64 + vg*4];
    short4v pk;
    #pragma unroll
    for (int rg = 0; rg < 4; rg++)
      pk[rg] = f2bf((w0*p0[rg] + w1*p1[rg])*inv);
    int n = qb*128 + q;
    *(short4v*)&Ows[(size_t)n*1024 + h*64 + vg*4] = pk;
  }
}

// ---- Y[f32] = O[4096x1024 bf16] @ Wot[1024x1024 bf16 B^T rows]
__global__ __launch_bounds__(256,2) void kfinal(const short* __restrict__ Ain,
                                                const short* __restrict__ Bt,
                                                float* __restrict__ Y)
{
  __shared__ short Al[128*48];
  __shared__ short Bl[64*48];
  int cb = blockIdx.x, rb = blockIdx.y;
  int row0 = rb*128, col0 = cb*64;
  int t = threadIdx.x, w = t >> 6, l = t & 63, quad = l >> 4, ln = l & 15;
  floatx4 acc[2][4] = {};
  for (int d0 = 0; d0 < 1024; d0 += 32){
    #pragma unroll
    for (int i = 0; i < 2; i++){
      int u = t + i*256, r = u >> 2, s = u & 3;
      *(int4*)&Al[r*48 + s*8] = *(const int4*)&Ain[(size_t)(row0 + r)*1024 + d0 + s*8];
    }
    { int r = t >> 2, s = t & 3;
      *(int4*)&Bl[r*48 + s*8] = *(const int4*)&Bt[(size_t)(col0 + r)*1024 + d0 + s*8]; }
    __syncthreads();
    short8 bf[4];
    #pragma unroll
    for (int nt = 0; nt < 4; nt++) bf[nt] = *(short8*)&Bl[(nt*16 + ln)*48 + quad*8];
    #pragma unroll
    for (int mt = 0; mt < 2; mt++){
      short8 af = *(short8*)&Al[(w*32 + mt*16 + ln)*48 + quad*8];
      #pragma unroll
      for (int nt = 0; nt < 4; nt++)
        acc[mt][nt] = __builtin_amdgcn_mfma_f32_16x16x32_bf16(af, bf[nt], acc[mt][nt], 0, 0, 0);
    }
    __syncthreads();
  }
  #pragma unroll
  for (int mt = 0; mt < 2; mt++)
    #pragma unroll
    for (int nt = 0; nt < 4; nt++)
      #pragma unroll
      for (int rg = 0; rg < 4; rg++){
        int n = row0 + w*32 + mt*16 + quad*4 + rg;
        int c = col0 + nt*16 + ln;
        Y[(size_t)n*1024 + c] = acc[mt][nt][rg];
      }
}

extern "C" void kernel_launch(void* const* d_in, const int* in_sizes, int n_in,
                              void* d_out, int out_size, void* d_ws, size_t ws_size,
                              hipStream_t stream){
  (void)in_sizes; (void)n_in; (void)out_size; (void)ws_size;
  const float* X    = (const float*)d_in[0];
  const float* Mm   = (const float*)d_in[1];
  const int*   mask = (const int*)d_in[2];
  const float* Wq   = (const float*)d_in[3];
  const float* Wk   = (const float*)d_in[4];
  const float* Wv   = (const float*)d_in[5];
  const float* Wo   = (const float*)d_in[6];
  float* Y = (float*)d_out;
  char* ws = (char*)d_ws;
  const size_t MB = 1024*1024;
  short*    XFh   = (short*)   (ws +  0*MB);   // dead after kproj2
  short*    XFl   = (short*)   (ws +  8*MB);   // dead after kproj2
  short*    MFh   = (short*)   (ws + 16*MB);   // dead after kproj2
  short*    MFl   = (short*)   (ws + 24*MB);   // dead after kproj2
  short*    WFh   = (short*)   (ws + 32*MB);   // 6MB, dead after kproj2
  short*    WFl   = (short*)   (ws + 38*MB);   // 6MB, dead after kproj2
  unsigned* bits  = (unsigned*)(ws + 44*MB);   // 2MB  [4096 n][128 kw]
  _Float16* QFh   = (_Float16*)(ws + 46*MB);
  _Float16* QFl   = (_Float16*)(ws + 54*MB);
  _Float16* KFh   = (_Float16*)(ws + 62*MB);
  _Float16* KFl   = (_Float16*)(ws + 70*MB);
  _Float16* VF    = (_Float16*)(ws + 78*MB);
  short*    Ows   = (short*)   (ws +  0*MB);   // alias XFh (post-kproj2)
  short*    Wot   = (short*)   (ws +  8*MB);   // alias XFl lower
  short*    Wotl  = (short*)   (ws + 10*MB);
  float*    OP    = (float*)   (ws + 12*MB);   // 32MB partial O (post-kproj2 region)
  float2*   ML    = (float2*)  (ws + 86*MB);   // 1MB  (m,l) partials

  kconvA<<<512, 256, 0, stream>>>(X, Mm, XFh, XFl, MFh, MFl);
  kconvW2<<<dim3(48,8), 256, 0, stream>>>(Wq, Wk, Wv, WFh, WFl);
  kmaskpack<<<2048, 256, 0, stream>>>(mask, bits);
  kproj2<<<dim3(48,32), 256, 0, stream>>>(XFh, XFl, MFh, MFl, WFh, WFl,
                                          QFh, QFl, KFh, KFl, VF);
  ktransw<<<dim3(32,32,1), 256, 0, stream>>>(Wo, Wot, Wotl, 1024, 1024);
  kattn4<<<1024, 256, 0, stream>>>(QFh, QFl, KFh, KFl, VF, bits, OP, ML);
  kcomb<<<512, 256, 0, stream>>>(OP, ML, Ows);
  kfinal<<<dim3(16,32), 256, 0, stream>>>(Ows, Wot, Y);
}

// Round 8
// 468.146 us; speedup vs baseline: 1.1699x; 1.1699x over previous
//
#include <hip/hip_runtime.h>

typedef _Float16 half8 __attribute__((ext_vector_type(8)));
typedef _Float16 half4 __attribute__((ext_vector_type(4)));
typedef __fp16 fp16x2 __attribute__((ext_vector_type(2)));
typedef short short8 __attribute__((ext_vector_type(8)));
typedef short short4v __attribute__((ext_vector_type(4)));
typedef float floatx4 __attribute__((ext_vector_type(4)));

#define LOG2E 1.4426950408889634f

#define GLDS16(g, l) __builtin_amdgcn_global_load_lds( \
    (const __attribute__((address_space(1))) unsigned int*)(g), \
    (__attribute__((address_space(3))) unsigned int*)(l), 16, 0, 0)

static __device__ __forceinline__ short f2bf(float f){
  union { float f; unsigned u; } v; v.f = f;
  unsigned r = v.u + 0x7fffu + ((v.u >> 16) & 1u);
  return (short)(r >> 16);
}
static __device__ __forceinline__ float bf2f(short s){
  union { unsigned u; float f; } v; v.u = ((unsigned)(unsigned short)s) << 16;
  return v.f;
}

// ---- X/M fp32 -> fragment-major bf16 hi/lo.  Frag layout: [kt(32)][ntile(256)][64][8]
__global__ __launch_bounds__(256) void kconvA(const float* __restrict__ X,
                                              const float* __restrict__ Mm,
                                              short* __restrict__ XFh, short* __restrict__ XFl,
                                              short* __restrict__ MFh, short* __restrict__ MFl){
  int b = blockIdx.x;                       // 512: src=b>>8, ntile=b&255
  int t = threadIdx.x, w = t >> 6, l = t & 63, quad = l >> 4;
  int srcsel = b >> 8, ntile = b & 255;
  const float* A = srcsel ? Mm : X;
  short* oh = srcsel ? MFh : XFh;
  short* ol = srcsel ? MFl : XFl;
  int row = ntile*16 + (l & 15);
  #pragma unroll
  for (int i = 0; i < 8; i++){
    int kt = w*8 + i;
    const float* p = A + (size_t)row*1024 + kt*32 + quad*8;
    float4 v0 = *(const float4*)p, v1 = *(const float4*)(p + 4);
    float vv[8] = {v0.x,v0.y,v0.z,v0.w,v1.x,v1.y,v1.z,v1.w};
    short8 hh, ll;
    #pragma unroll
    for (int j = 0; j < 8; j++){
      short hb = f2bf(vv[j]); hh[j] = hb; ll[j] = f2bf(vv[j] - bf2f(hb));
    }
    size_t off = ((size_t)kt*256 + ntile)*512 + l*8;
    *(short8*)&oh[off] = hh;
    *(short8*)&ol[off] = ll;
  }
}

// ---- Wq/Wk/Wv fp32 [h][1024][64] -> fragment-major bf16 hi/lo, LDS-staged coalesced
__global__ __launch_bounds__(256) void kconvW2(const float* __restrict__ Wq,
                                               const float* __restrict__ Wk,
                                               const float* __restrict__ Wv,
                                               short* __restrict__ WFh, short* __restrict__ WFl){
  __shared__ float T[128][68];
  int bidx = blockIdx.x, g = blockIdx.y;    // bidx 0..47, g 0..7 (4 kt each)
  int mat = bidx >> 4, h = bidx & 15;
  const float* W = (mat == 0 ? Wq : (mat == 1 ? Wk : Wv)) + (size_t)h*65536;
  int t = threadIdx.x, w = t >> 6, l = t & 63, quad = (l >> 4) & 3, fl = l & 15;
  #pragma unroll
  for (int p = 0; p < 32; p++){
    int idx = p*256 + t, row = idx >> 6, col = idx & 63;
    T[row][col] = W[(size_t)(g*128 + row)*64 + col];
  }
  __syncthreads();
  for (int ktl = 0; ktl < 4; ktl++){
    short8 hh, ll;
    #pragma unroll
    for (int j = 0; j < 8; j++){
      float v = T[ktl*32 + quad*8 + j][w*16 + fl];
      short hb = f2bf(v); hh[j] = hb; ll[j] = f2bf(v - bf2f(hb));
    }
    size_t frag = ((size_t)bidx*32 + g*4 + ktl)*4 + w;
    *(short8*)&WFh[frag*512 + l*8] = hh;
    *(short8*)&WFl[frag*512 + l*8] = ll;
  }
}

// ---- mask -> bitmask (row orientation): bits[n*128 + kw] bit i = mask[n][kw*32+i]
__global__ __launch_bounds__(256) void kmaskpack(const int* __restrict__ mask,
                                                 unsigned* __restrict__ bits){
  int w = blockIdx.x * 256 + threadIdx.x;          // 4096*128 words
  const int* p = mask + (size_t)w * 32;
  unsigned b = 0;
  #pragma unroll
  for (int i = 0; i < 32; i++) b |= (p[i] != 0) ? (1u << i) : 0u;
  bits[w] = b;
}

// ---- fp32 [R][C] (z-batch) -> transposed bf16 hi/lo [C][R]  (for Wo)
__global__ __launch_bounds__(256) void ktransw(const float* __restrict__ src,
                                               short* __restrict__ dsth,
                                               short* __restrict__ dstl,
                                               int R, int C){
  __shared__ float tile[32][33];
  size_t boff = (size_t)blockIdx.z * R * C;
  src += boff; dsth += boff; dstl += boff;
  int r0 = blockIdx.y*32, c0 = blockIdx.x*32;
  int t = threadIdx.x, tr = t >> 3, tc = (t & 7)*4;
  const float* s = src + (size_t)(r0 + tr)*C + c0 + tc;
  #pragma unroll
  for (int i = 0; i < 4; i++) tile[tr][tc + i] = s[i];
  __syncthreads();
  short* dh = dsth + (size_t)(c0 + tr)*R + r0 + tc;
  short* dl = dstl + (size_t)(c0 + tr)*R + r0 + tc;
  #pragma unroll
  for (int i = 0; i < 4; i++){
    float v = tile[tc + i][tr];
    short hb = f2bf(v);
    dh[i] = hb; dl[i] = f2bf(v - bf2f(hb));
  }
}

// ---- QKV projection: fragment-major in/out. Q/K f16 hi/lo (Q pre-scaled by log2 e);
//      V stored as K=16 A-fragments for mfma_f32_16x16x16f16 PV.
__global__ __launch_bounds__(256,2) void kproj2(
    const short* __restrict__ XFh, const short* __restrict__ XFl,
    const short* __restrict__ MFh, const short* __restrict__ MFl,
    const short* __restrict__ WFh, const short* __restrict__ WFl,
    _Float16* __restrict__ QFh, _Float16* __restrict__ QFl,
    _Float16* __restrict__ KFh, _Float16* __restrict__ KFl,
    _Float16* __restrict__ VF)
{
  __shared__ short AhL[4096], AlL[4096], BhL[2048], BlL[2048];
  int cb = blockIdx.x, rb = blockIdx.y;
  int mat = cb >> 4, h = cb & 15;
  const short* Ah = (mat == 0) ? XFh : MFh;
  const short* Al = (mat == 0) ? XFl : MFl;
  int t = threadIdx.x, w = t >> 6, l = t & 63, quad = l >> 4, ln = l & 15;
  floatx4 acc[2][4] = {};
  for (int kt = 0; kt < 32; kt++){
    __syncthreads();
    size_t abase = ((size_t)kt*256 + rb*8)*512;
    #pragma unroll
    for (int i = 0; i < 2; i++){
      int cidx = i*256 + t;
      GLDS16(Ah + abase + cidx*8, &AhL[(i*256 + w*64)*8]);
      GLDS16(Al + abase + cidx*8, &AlL[(i*256 + w*64)*8]);
    }
    size_t bbase = (((size_t)cb*32 + kt)*4)*512;
    GLDS16(WFh + bbase + t*8, &BhL[(w*64)*8]);
    GLDS16(WFl + bbase + t*8, &BlL[(w*64)*8]);
    __syncthreads();
    short8 bh[4], bl[4];
    #pragma unroll
    for (int nt = 0; nt < 4; nt++){
      bh[nt] = *(short8*)&BhL[nt*512 + l*8];
      bl[nt] = *(short8*)&BlL[nt*512 + l*8];
    }
    #pragma unroll
    for (int mt = 0; mt < 2; mt++){
      short8 ah = *(short8*)&AhL[(w*2 + mt)*512 + l*8];
      short8 al = *(short8*)&AlL[(w*2 + mt)*512 + l*8];
      #pragma unroll
      for (int nt = 0; nt < 4; nt++){
        acc[mt][nt] = __builtin_amdgcn_mfma_f32_16x16x32_bf16(ah, bh[nt], acc[mt][nt], 0, 0, 0);
        acc[mt][nt] = __builtin_amdgcn_mfma_f32_16x16x32_bf16(ah, bl[nt], acc[mt][nt], 0, 0, 0);
        acc[mt][nt] = __builtin_amdgcn_mfma_f32_16x16x32_bf16(al, bh[nt], acc[mt][nt], 0, 0, 0);
      }
    }
  }
  int row0 = rb*128;
  if (mat == 2){
    // V: K=16 A-frag layout. m = row0 + w*32 + mt*16 + quad*4 + rg, v = nt*16 + ln.
    // kt=rb, p=w, sub=mt, lane'=quad*16+ln, j=rg  ->  8B store per (mt,nt).
    #pragma unroll
    for (int mt = 0; mt < 2; mt++)
      #pragma unroll
      for (int nt = 0; nt < 4; nt++){
        union { fp16x2 h2[2]; unsigned u2[2]; } pu;
        pu.h2[0] = __builtin_amdgcn_cvt_pkrtz(acc[mt][nt][0], acc[mt][nt][1]);
        pu.h2[1] = __builtin_amdgcn_cvt_pkrtz(acc[mt][nt][2], acc[mt][nt][3]);
        size_t base = (((size_t)h*32 + rb)*16 + nt*4 + w)*512;
        *(uint2*)&VF[base + (quad*16 + ln)*8 + mt*4] = *(uint2*)&pu.u2[0];
      }
  } else {
    #pragma unroll
    for (int mt = 0; mt < 2; mt++)
      #pragma unroll
      for (int nt = 0; nt < 4; nt++)
        #pragma unroll
        for (int rg = 0; rg < 4; rg++){
          int n = row0 + w*32 + mt*16 + quad*4 + rg;
          int c = nt*16 + ln;
          float v = acc[mt][nt][rg];
          if (mat == 0) v *= LOG2E;             // log2-domain logits
          _Float16 hi = (_Float16)v;
          _Float16 lo = (_Float16)(v - (float)hi);
          int lane2 = (n & 15) + (((c >> 3) & 3) << 4);
          size_t off = (((size_t)h*256 + (n >> 4))*2 + (c >> 5))*512 + lane2*8 + (c & 7);
          if (mat == 0){ QFh[off] = hi; QFl[off] = lo; }
          else         { KFh[off] = hi; KFl[off] = lo; }
        }
  }
}

// ---- flash attention v5: single pass, 48KB LDS (3 blocks/CU), S^T=K*Q^T,
//      PV via mfma_16x16x16f16 consuming P accumulator registers directly (no P LDS)
__global__ __launch_bounds__(256,3) void kattn5(
    const _Float16* __restrict__ QFh, const _Float16* __restrict__ QFl,
    const _Float16* __restrict__ KFh, const _Float16* __restrict__ KFl,
    const _Float16* __restrict__ VF, const unsigned* __restrict__ bits,
    short* __restrict__ Ows)
{
  __shared__ _Float16 KBh[8192], KBl[8192], VB[8192];     // 48 KB exactly
  int bx = blockIdx.x, h = bx & 15, qb = bx >> 4, q0 = qb*128;
  int t = threadIdx.x, w = t >> 6, l = t & 63, quad = l >> 4, ln = l & 15;

  // Q as B-fragments (col q = ln, k = quad*8+j per 32-d chunk)
  half8 qh[2][2], ql[2][2];
  #pragma unroll
  for (int nt2 = 0; nt2 < 2; nt2++)
    #pragma unroll
    for (int kc = 0; kc < 2; kc++){
      size_t off = (((size_t)h*256 + qb*8 + w*2 + nt2)*2 + kc)*512 + l*8;
      qh[nt2][kc] = *(const half8*)&QFh[off];
      ql[nt2][kc] = *(const half8*)&QFl[off];
    }

  floatx4 o[2][4] = {};                       // O^T: lane q=ln, v = vt*16+quad*4+rg
  float mst[2] = {-1e30f, -1e30f}, lst[2] = {0.f, 0.f};

  for (int kt = 0; kt < 32; kt++){
    __syncthreads();
    size_t kb = (size_t)h*262144 + (size_t)kt*8192;
    #pragma unroll
    for (int i = 0; i < 4; i++){
      int cidx = i*256 + t;
      GLDS16(KFh + kb + cidx*8, &KBh[(i*256 + w*64)*8]);
      GLDS16(KFl + kb + cidx*8, &KBl[(i*256 + w*64)*8]);
      GLDS16(VF  + kb + cidx*8, &VB [(i*256 + w*64)*8]);
    }
    uint4 mw[2];
    mw[0] = *(const uint4*)&bits[(size_t)(q0 + w*32 + ln)*128 + kt*4];
    mw[1] = *(const uint4*)&bits[(size_t)(q0 + w*32 + 16 + ln)*128 + kt*4];
    __syncthreads();

    // S^T = Khi*Qhi + Klo*Qhi + Khi*Qlo  (log2-domain; K-frags read once)
    floatx4 st[2][8] = {};
    #pragma unroll
    for (int kc = 0; kc < 2; kc++)
      #pragma unroll
      for (int m8 = 0; m8 < 8; m8++){
        half8 kh = *(half8*)&KBh[(m8*2 + kc)*512 + l*8];
        half8 kl = *(half8*)&KBl[(m8*2 + kc)*512 + l*8];
        #pragma unroll
        for (int nt2 = 0; nt2 < 2; nt2++){
          st[nt2][m8] = __builtin_amdgcn_mfma_f32_16x16x32_f16(kh, qh[nt2][kc], st[nt2][m8], 0, 0, 0);
          st[nt2][m8] = __builtin_amdgcn_mfma_f32_16x16x32_f16(kl, qh[nt2][kc], st[nt2][m8], 0, 0, 0);
          st[nt2][m8] = __builtin_amdgcn_mfma_f32_16x16x32_f16(kh, ql[nt2][kc], st[nt2][m8], 0, 0, 0);
        }
      }

    // mask + online softmax (register bit-test), then p = 2^(s - m)
    #pragma unroll
    for (int nt2 = 0; nt2 < 2; nt2++){
      const unsigned* mwp = (const unsigned*)&mw[nt2];
      #pragma unroll
      for (int m8 = 0; m8 < 8; m8++){
        unsigned nib = (mwp[m8 >> 1] >> ((m8 & 1)*16 + quad*4)) & 15u;
        #pragma unroll
        for (int rg = 0; rg < 4; rg++)
          if (!((nib >> rg) & 1u)) st[nt2][m8][rg] = -1e30f;
      }
      float mx = st[nt2][0][0];
      #pragma unroll
      for (int m8 = 0; m8 < 8; m8++)
        #pragma unroll
        for (int rg = 0; rg < 4; rg++) mx = fmaxf(mx, st[nt2][m8][rg]);
      mx = fmaxf(mx, __shfl_xor(mx, 16));
      mx = fmaxf(mx, __shfl_xor(mx, 32));
      float mnew = fmaxf(mst[nt2], mx);
      float alpha = exp2f(mst[nt2] - mnew);
      mst[nt2] = mnew;
      lst[nt2] *= alpha;
      #pragma unroll
      for (int vt = 0; vt < 4; vt++) o[nt2][vt] *= alpha;
      float ssum = 0.f;
      #pragma unroll
      for (int m8 = 0; m8 < 8; m8++)
        #pragma unroll
        for (int rg = 0; rg < 4; rg++){
          float p = exp2f(st[nt2][m8][rg] - mnew);
          st[nt2][m8][rg] = p; ssum += p;
        }
      ssum += __shfl_xor(ssum, 16);
      ssum += __shfl_xor(ssum, 32);
      lst[nt2] += ssum;
    }

    // PV: P C-layout == B-operand of 16x16x16f16 (k = quad*4+rg), zero transpose.
    #pragma unroll
    for (int p = 0; p < 4; p++){
      half8 vfp[4];
      #pragma unroll
      for (int vt = 0; vt < 4; vt++)
        vfp[vt] = *(half8*)&VB[(vt*4 + p)*512 + l*8];
      #pragma unroll
      for (int nt2 = 0; nt2 < 2; nt2++)
        #pragma unroll
        for (int sub = 0; sub < 2; sub++){
          int m8 = p*2 + sub;
          union { fp16x2 h2[2]; half4 h4; } pu;
          pu.h2[0] = __builtin_amdgcn_cvt_pkrtz(st[nt2][m8][0], st[nt2][m8][1]);
          pu.h2[1] = __builtin_amdgcn_cvt_pkrtz(st[nt2][m8][2], st[nt2][m8][3]);
          #pragma unroll
          for (int vt = 0; vt < 4; vt++){
            half4 va = sub ? __builtin_shufflevector(vfp[vt], vfp[vt], 4,5,6,7)
                           : __builtin_shufflevector(vfp[vt], vfp[vt], 0,1,2,3);
            o[nt2][vt] = __builtin_amdgcn_mfma_f32_16x16x16f16(va, pu.h4, o[nt2][vt], 0, 0, 0);
          }
        }
    }
  }

  // epilogue: normalize, O^T -> Ows[n][h*64+v], 8B packed stores
  #pragma unroll
  for (int nt2 = 0; nt2 < 2; nt2++){
    float li = lst[nt2];
    float inv = (li > 0.f) ? (1.f / li) : 0.f;
    int n = q0 + w*32 + nt2*16 + ln;
    #pragma unroll
    for (int vt = 0; vt < 4; vt++){
      short4v pk;
      #pragma unroll
      for (int rg = 0; rg < 4; rg++) pk[rg] = f2bf(o[nt2][vt][rg]*inv);
      *(short4v*)&Ows[(size_t)n*1024 + h*64 + vt*16 + quad*4] = pk;
    }
  }
}

// ---- Y[f32] = O[4096x1024 bf16] @ Wot[1024x1024 bf16 B^T rows]
__global__ __launch_bounds__(256,2) void kfinal(const short* __restrict__ Ain,
                                                const short* __restrict__ Bt,
                                                float* __restrict__ Y)
{
  __shared__ short Al[128*48];
  __shared__ short Bl[64*48];
  int cb = blockIdx.x, rb = blockIdx.y;
  int row0 = rb*128, col0 = cb*64;
  int t = threadIdx.x, w = t >> 6, l = t & 63, quad = l >> 4, ln = l & 15;
  floatx4 acc[2][4] = {};
  for (int d0 = 0; d0 < 1024; d0 += 32){
    #pragma unroll
    for (int i = 0; i < 2; i++){
      int u = t + i*256, r = u >> 2, s = u & 3;
      *(int4*)&Al[r*48 + s*8] = *(const int4*)&Ain[(size_t)(row0 + r)*1024 + d0 + s*8];
    }
    { int r = t >> 2, s = t & 3;
      *(int4*)&Bl[r*48 + s*8] = *(const int4*)&Bt[(size_t)(col0 + r)*1024 + d0 + s*8]; }
    __syncthreads();
    short8 bf[4];
    #pragma unroll
    for (int nt = 0; nt < 4; nt++) bf[nt] = *(short8*)&Bl[(nt*16 + ln)*48 + quad*8];
    #pragma unroll
    for (int mt = 0; mt < 2; mt++){
      short8 af = *(short8*)&Al[(w*32 + mt*16 + ln)*48 + quad*8];
      #pragma unroll
      for (int nt = 0; nt < 4; nt++)
        acc[mt][nt] = __builtin_amdgcn_mfma_f32_16x16x32_bf16(af, bf[nt], acc[mt][nt], 0, 0, 0);
    }
    __syncthreads();
  }
  #pragma unroll
  for (int mt = 0; mt < 2; mt++)
    #pragma unroll
    for (int nt = 0; nt < 4; nt++)
      #pragma unroll
      for (int rg = 0; rg < 4; rg++){
        int n = row0 + w*32 + mt*16 + quad*4 + rg;
        int c = col0 + nt*16 + ln;
        Y[(size_t)n*1024 + c] = acc[mt][nt][rg];
      }
}

extern "C" void kernel_launch(void* const* d_in, const int* in_sizes, int n_in,
                              void* d_out, int out_size, void* d_ws, size_t ws_size,
                              hipStream_t stream){
  (void)in_sizes; (void)n_in; (void)out_size; (void)ws_size;
  const float* X    = (const float*)d_in[0];
  const float* Mm   = (const float*)d_in[1];
  const int*   mask = (const int*)d_in[2];
  const float* Wq   = (const float*)d_in[3];
  const float* Wk   = (const float*)d_in[4];
  const float* Wv   = (const float*)d_in[5];
  const float* Wo   = (const float*)d_in[6];
  float* Y = (float*)d_out;
  char* ws = (char*)d_ws;
  const size_t MB = 1024*1024;
  short*    XFh   = (short*)   (ws +  0*MB);   // dead after kproj2
  short*    XFl   = (short*)   (ws +  8*MB);   // dead after kproj2
  short*    MFh   = (short*)   (ws + 16*MB);
  short*    MFl   = (short*)   (ws + 24*MB);
  short*    WFh   = (short*)   (ws + 32*MB);   // 6MB
  short*    WFl   = (short*)   (ws + 38*MB);   // 6MB
  unsigned* bits  = (unsigned*)(ws + 44*MB);   // 2MB  [4096 n][128 kw]
  _Float16* QFh   = (_Float16*)(ws + 46*MB);
  _Float16* QFl   = (_Float16*)(ws + 54*MB);
  _Float16* KFh   = (_Float16*)(ws + 62*MB);
  _Float16* KFl   = (_Float16*)(ws + 70*MB);
  _Float16* VF    = (_Float16*)(ws + 78*MB);   // 8MB, K=16 A-frag layout
  short*    Ows   = (short*)   (ws +  0*MB);   // alias XFh (post-kproj2)
  short*    Wot   = (short*)   (ws +  8*MB);   // alias XFl
  short*    Wotl  = (short*)   (ws + 10*MB);

  kconvA<<<512, 256, 0, stream>>>(X, Mm, XFh, XFl, MFh, MFl);
  kconvW2<<<dim3(48,8), 256, 0, stream>>>(Wq, Wk, Wv, WFh, WFl);
  kmaskpack<<<2048, 256, 0, stream>>>(mask, bits);
  kproj2<<<dim3(48,32), 256, 0, stream>>>(XFh, XFl, MFh, MFl, WFh, WFl,
                                          QFh, QFl, KFh, KFl, VF);
  ktransw<<<dim3(32,32,1), 256, 0, stream>>>(Wo, Wot, Wotl, 1024, 1024);
  kattn5<<<512, 256, 0, stream>>>(QFh, QFl, KFh, KFl, VF, bits, Ows);
  kfinal<<<dim3(16,32), 256, 0, stream>>>(Ows, Wot, Y);
}